// Round 12
// baseline (155.388 us; speedup 1.0000x reference)
//
#include <hip/hip_runtime.h>
#include <stdint.h>

#define T_STEPS 100
#define BB 4
#define NN 512
#define KK 10
#define LOG2E 1.4426950408889634

typedef float f4 __attribute__((ext_vector_type(4)));

// ---------------- threefry2x32 (JAX-compatible, 20 rounds) ----------------
__device__ __forceinline__ uint32_t rotl32(uint32_t v, int d) {
  return (v << d) | (v >> (32 - d));
}

__device__ __forceinline__ void tf2x32(uint32_t k0, uint32_t k1,
                                       uint32_t& x0, uint32_t& x1) {
  uint32_t k2 = k0 ^ k1 ^ 0x1BD11BDAu;
  x0 += k0; x1 += k1;
#define TFR(r) { x0 += x1; x1 = rotl32(x1, r); x1 ^= x0; }
  TFR(13) TFR(15) TFR(26) TFR(6)   x0 += k1; x1 += k2 + 1u;
  TFR(17) TFR(29) TFR(16) TFR(24)  x0 += k2; x1 += k0 + 2u;
  TFR(13) TFR(15) TFR(26) TFR(6)   x0 += k0; x1 += k1 + 3u;
  TFR(17) TFR(29) TFR(16) TFR(24)  x0 += k1; x1 += k2 + 4u;
  TFR(13) TFR(15) TFR(26) TFR(6)   x0 += k2; x1 += k0 + 5u;
#undef TFR
}

__device__ __forceinline__ float bits_to_u01(uint32_t bits) {
  return __fsub_rn(__uint_as_float((bits >> 9) | 0x3f800000u), 1.0f);
}

// XLA ErfInv32 (Giles)
__device__ __forceinline__ float erfinv_f32(float x) {
  float w = -logf(__fmul_rn(__fsub_rn(1.0f, x), __fadd_rn(1.0f, x)));
  float p;
  if (w < 5.0f) {
    w = __fsub_rn(w, 2.5f);
    p = 2.81022636e-08f;
    p = __fadd_rn(__fmul_rn(p, w), 3.43273939e-07f);
    p = __fadd_rn(__fmul_rn(p, w), -3.5233877e-06f);
    p = __fadd_rn(__fmul_rn(p, w), -4.39150654e-06f);
    p = __fadd_rn(__fmul_rn(p, w), 0.00021858087f);
    p = __fadd_rn(__fmul_rn(p, w), -0.00125372503f);
    p = __fadd_rn(__fmul_rn(p, w), -0.00417768164f);
    p = __fadd_rn(__fmul_rn(p, w), 0.246640727f);
    p = __fadd_rn(__fmul_rn(p, w), 1.50140941f);
  } else {
    w = __fsub_rn(sqrtf(w), 3.0f);
    p = -0.000200214257f;
    p = __fadd_rn(__fmul_rn(p, w), 0.000100950558f);
    p = __fadd_rn(__fmul_rn(p, w), 0.00134934322f);
    p = __fadd_rn(__fmul_rn(p, w), -0.00367342844f);
    p = __fadd_rn(__fmul_rn(p, w), 0.00573950773f);
    p = __fadd_rn(__fmul_rn(p, w), -0.0076224613f);
    p = __fadd_rn(__fmul_rn(p, w), 0.00943887047f);
    p = __fadd_rn(__fmul_rn(p, w), 1.00167406f);
    p = __fadd_rn(__fmul_rn(p, w), 2.83297682f);
  }
  return __fmul_rn(p, x);
}

// fast sigmoid: 1/(1+exp(-x)) via native exp + native rcp
__device__ __forceinline__ float fast_sigmoid(float x) {
  float e = __expf(-x);
  return __builtin_amdgcn_rcpf(__fadd_rn(1.0f, e));
}

template <int CTRL>
__device__ __forceinline__ float dpp_add(float x) {
  int v = __builtin_amdgcn_update_dpp(0, __float_as_int(x), CTRL, 0xF, 0xF, true);
  return __fadd_rn(x, __int_as_float(v));
}
__device__ __forceinline__ float readlane_f(float x, int lane) {
  return __int_as_float(__builtin_amdgcn_readlane(__float_as_int(x), lane));
}

// ------ Kernel B: RNG + merged prep (per-thread softmax recompute) ----------
__global__ void rng_kernel(const float* __restrict__ mu,
                           const float* __restrict__ sig,
                           const float* __restrict__ pi,
                           float* __restrict__ pm, float* __restrict__ uacc,
                           float* __restrict__ Lf) {
  int id = blockIdx.x * blockDim.x + threadIdx.x;
  if (id >= T_STEPS * BB * NN) return;
  int t = id >> 11;        // /2048
  int m = id & 2047;       // b*512+n

  const float* pp = pi + m * KK;
  float mx = pp[0];
  for (int k = 1; k < KK; k++) mx = fmaxf(mx, pp[k]);
  float e[KK]; float s = 0.0f;
  for (int k = 0; k < KK; k++) { e[k] = expf(__fsub_rn(pp[k], mx)); s = __fadd_rn(s, e[k]); }
  float smv = 0.0f, ssv = 0.0f, eps = 0.0f;
  for (int k = 0; k < KK; k++) {
    float p = e[k] / s;
    smv = __fadd_rn(smv, __fmul_rn(p, mu[m * KK + k]));
    ssv = __fadd_rn(ssv, __fmul_rn(p, sig[m * KK + k]));
    eps = __fadd_rn(eps, pp[k]);
  }
  if (t == 0) {
    float ep = fminf(fmaxf(eps, 1e-8f), 1.0f);
    float lep = logf(ep);
    float l1 = logf(__fsub_rn(1.0f, ep));
    Lf[m] = (float)((double)lep - (double)l1);
  }

  uint32_t kk0 = 0u, kk1 = (uint32_t)t;
  tf2x32(0u, 42u, kk0, kk1);
  uint32_t n0 = 0u, n1 = 0u; tf2x32(kk0, kk1, n0, n1);   // k_noise
  uint32_t y0 = 0u, y1 = (uint32_t)m;
  tf2x32(n0, n1, y0, y1);
  uint32_t bits = y0 ^ y1;

  float u01 = bits_to_u01(bits);
  const float lo = -0.99999994f;
  float u = fmaxf(lo, __fadd_rn(__fmul_rn(u01, 2.0f), lo));
  float z = __fmul_rn(1.41421356237309515f, erfinv_f32(u));
  pm[id] = __fadd_rn(smv, __fmul_rn(z, ssv));

  if (m < 4) {
    uint32_t u0 = 0u, u1 = 1u; tf2x32(kk0, kk1, u0, u1); // k_unif
    uint32_t c0 = 0u, c1 = (uint32_t)m;
    tf2x32(u0, u1, c0, c1);
    uacc[t * 4 + m] = __fmul_rn(bits_to_u01(c0 ^ c1), 512.0f);  // pre-x512
  }
}

// ------ Kernel C: llt rows (bit-identical to verified) + Tsum = sum_b ------
// blocks [0,400): (t, jc) — all 4 batches; blocks [400,416): ll0 (b, jc).
__global__ __launch_bounds__(512) void ll_kernel(const float* __restrict__ pm,
                                                 const float* __restrict__ Lf,
                                                 const float* __restrict__ A0,
                                                 float* __restrict__ llt,
                                                 float* __restrict__ ll0,
                                                 float* __restrict__ tsum) {
  __shared__ float spm[BB][NN];
  __shared__ float sL[BB][NN];
  __shared__ double pt[4][128];
  int tid = threadIdx.x;
  int q = tid >> 7, jj = tid & 127;
  int bi = blockIdx.x;
  if (bi < 400) {
    int t = bi >> 2, jc = bi & 3;
    #pragma unroll
    for (int b = 0; b < BB; b++) {
      spm[b][tid] = pm[(t * 4 + b) * NN + tid];
      sL[b][tid] = Lf[b * NN + tid];
    }
    __syncthreads();
    int i0 = q * 128;
    double tsd = 0.0;
    for (int b = 0; b < BB; b++) {
      float pmj = spm[b][jc * 128 + jj];
      double acc = 0.0;
      #pragma unroll 8
      for (int i = 0; i < 128; i += 2) {
        float x0 = __fmul_rn(spm[b][i0 + i], pmj);
        float x1 = __fmul_rn(spm[b][i0 + i + 1], pmj);
        float t0 = __fmul_rn(fast_sigmoid(x0), sL[b][i0 + i]);
        float t1 = __fmul_rn(fast_sigmoid(x1), sL[b][i0 + i + 1]);
        acc += (double)__fadd_rn(t0, t1);
      }
      pt[q][jj] = acc;
      __syncthreads();
      if (tid < 128) {
        double a = ((pt[0][jj] + pt[1][jj]) + pt[2][jj]) + pt[3][jj];
        llt[(t * 4 + b) * NN + jc * 128 + jj] = (float)(a * LOG2E);
        tsd += a;
      }
      __syncthreads();
    }
    if (tid < 128) tsum[t * NN + jc * 128 + jj] = (float)(tsd * LOG2E);
  } else {
    int idx = bi - 400;
    int b = idx >> 2, jc = idx & 3;
    sL[0][tid] = Lf[b * NN + tid];
    __syncthreads();
    int j = jc * 128 + jj;
    int i0 = q * 128;
    double acc = 0.0;
    #pragma unroll 4
    for (int i = 0; i < 128; i++) {
      acc += (double)A0[(size_t)(i0 + i) * NN + j] * (double)sL[0][i0 + i];
    }
    pt[q][jj] = acc;
    __syncthreads();
    if (tid < 128) {
      double a = ((pt[0][jj] + pt[1][jj]) + pt[2][jj]) + pt[3][jj];
      ll0[b * NN + jc * 128 + jj] = (float)(a * LOG2E);
    }
  }
}

// ------- Kernel D: single-wave chain, short critical path -------------------
// lane g owns j = k*256 + 4g + c.  Compute path per step: Ts(2 f4 load) - C
// -> 8 exp2 -> intra tree -> 4 DPP -> 4 readlane + 3 adds -> compare.
// Accept work (row copies + C recompute) behind wave-uniform scalar branch.
#define CH_LOAD(BUF, T)                                                      \
  {                                                                          \
    BUF##Ts0 = tsv[(size_t)(T) * 128 + g];                                   \
    BUF##Ts1 = tsv[(size_t)(T) * 128 + 64 + g];                              \
    _Pragma("unroll")                                                        \
    for (int b = 0; b < 4; b++) {                                            \
      _Pragma("unroll")                                                      \
      for (int k = 0; k < 2; k++)                                            \
        BUF##R[b * 2 + k] = lltv[((size_t)(T) * 4 + b) * 128 + k * 64 + g];  \
    }                                                                        \
  }

#define CH_STEP(BUF, T)                                                      \
  {                                                                          \
    float4 ua = sua[T];                                                      \
    f4 d0 = BUF##Ts0 - C0;                                                   \
    f4 d1 = BUF##Ts1 - C1;                                                   \
    f4 E0, E1;                                                               \
    _Pragma("unroll")                                                        \
    for (int c = 0; c < 4; c++) {                                            \
      E0[c] = fminf(exp2f(d0[c]), 1.0f);                                     \
      E1[c] = fminf(exp2f(d1[c]), 1.0f);                                     \
    }                                                                        \
    f4 Es = E0 + E1;                                                         \
    float ps = __fadd_rn(__fadd_rn(Es[0], Es[1]), __fadd_rn(Es[2], Es[3]));  \
    ps = dpp_add<0xB1>(ps);   /* xor1 */                                     \
    ps = dpp_add<0x4E>(ps);   /* xor2 */                                     \
    ps = dpp_add<0x141>(ps);  /* xor4 (half-mirror) */                       \
    ps = dpp_add<0x140>(ps);  /* xor8 (mirror) */                            \
    float s0 = readlane_f(ps, 0), s1 = readlane_f(ps, 16);                   \
    float s2 = readlane_f(ps, 32), s3 = readlane_f(ps, 48);                  \
    float tot = __fadd_rn(__fadd_rn(s0, s1), __fadd_rn(s2, s3));             \
    int am = (ua.x < tot ? 1 : 0) | (ua.y < tot ? 2 : 0) |                   \
             (ua.z < tot ? 4 : 0) | (ua.w < tot ? 8 : 0);                    \
    am = __builtin_amdgcn_readfirstlane(am);                                 \
    if (am) {                                                                \
      if (am & 1) { st0 = (T); cur[0] = BUF##R[0]; cur[1] = BUF##R[1]; }     \
      if (am & 2) { st1 = (T); cur[2] = BUF##R[2]; cur[3] = BUF##R[3]; }     \
      if (am & 4) { st2 = (T); cur[4] = BUF##R[4]; cur[5] = BUF##R[5]; }     \
      if (am & 8) { st3 = (T); cur[6] = BUF##R[6]; cur[7] = BUF##R[7]; }     \
      C0 = (cur[0] + cur[2]) + (cur[4] + cur[6]);                            \
      C1 = (cur[1] + cur[3]) + (cur[5] + cur[7]);                            \
    }                                                                        \
    if (g == 0) {                                                            \
      uint32_t pk = (uint32_t)(st0 + 1) | ((uint32_t)(st1 + 1) << 8) |       \
                    ((uint32_t)(st2 + 1) << 16) | ((uint32_t)(st3 + 1) << 24);\
      spk[T] = pk;                                                           \
    }                                                                        \
  }

__global__ __launch_bounds__(64, 1) void chain_kernel(const float* __restrict__ llt,
                                                      const float* __restrict__ tsum,
                                                      const float* __restrict__ ll0,
                                                      const float* __restrict__ uacc,
                                                      int* __restrict__ slist,
                                                      float* __restrict__ wlist,
                                                      int* __restrict__ Mv) {
  __shared__ float4 sua[T_STEPS];
  __shared__ uint32_t spk[T_STEPS];
  __shared__ int scnt[BB][101];
  int g = threadIdx.x;

  const float4* uacc4 = (const float4*)uacc;
  for (int t = g; t < T_STEPS; t += 64) sua[t] = uacc4[t];

  const f4* lltv = (const f4*)llt;
  const f4* tsv  = (const f4*)tsum;
  const f4* ll0v = (const f4*)ll0;

  f4 cur[8];
  #pragma unroll
  for (int b = 0; b < 4; b++)
    #pragma unroll
    for (int k = 0; k < 2; k++) cur[b * 2 + k] = ll0v[b * 128 + k * 64 + g];
  f4 C0 = (cur[0] + cur[2]) + (cur[4] + cur[6]);
  f4 C1 = (cur[1] + cur[3]) + (cur[5] + cur[7]);
  int st0 = -1, st1 = -1, st2 = -1, st3 = -1;

  f4 ATs0, ATs1, AR[8];
  f4 BTs0, BTs1, BR[8];
  CH_LOAD(A, 0)
  CH_LOAD(B, 1)
  __syncthreads();  // single wave; orders sua writes (cheap)

  for (int t = 0; t < T_STEPS; t += 2) {
    CH_STEP(A, t)
    if (t + 2 < T_STEPS) CH_LOAD(A, t + 2)
    CH_STEP(B, t + 1)
    if (t + 3 < T_STEPS) CH_LOAD(B, t + 3)
  }

  // ---- epilogue: histogram + compacted (state, weight) list ----
  __syncthreads();
  for (int s = g; s < BB * 101; s += 64) (&scnt[0][0])[s] = 0;
  __syncthreads();
  {
    uint32_t p0 = spk[g];
    atomicAdd(&scnt[0][p0 & 255], 1);
    atomicAdd(&scnt[1][(p0 >> 8) & 255], 1);
    atomicAdd(&scnt[2][(p0 >> 16) & 255], 1);
    atomicAdd(&scnt[3][p0 >> 24], 1);
    if (g < T_STEPS - 64) {
      uint32_t p1 = spk[64 + g];
      atomicAdd(&scnt[0][p1 & 255], 1);
      atomicAdd(&scnt[1][(p1 >> 8) & 255], 1);
      atomicAdd(&scnt[2][(p1 >> 16) & 255], 1);
      atomicAdd(&scnt[3][p1 >> 24], 1);
    }
  }
  __syncthreads();
  if (g < 4) {
    int m = 0;
    for (int s = 0; s <= 100; s++) {
      int c = scnt[g][s];
      if (c) { slist[g * 104 + m] = s; wlist[g * 104 + m] = (float)c; m++; }
    }
    Mv[g] = m;
  }
}

// ---------------- Kernel E: out via compacted state list --------------------
__global__ __launch_bounds__(512) void out_kernel(const float* __restrict__ pm,
                                                  const float* __restrict__ A0,
                                                  const int* __restrict__ slist,
                                                  const float* __restrict__ wlist,
                                                  const int* __restrict__ Mv,
                                                  float* __restrict__ out) {
  int b = blockIdx.x >> 9;
  int i = blockIdx.x & 511;
  int j = threadIdx.x;
  int M = Mv[b];
  float r = 0.0f;
  for (int e = 0; e < M; e++) {
    int s = slist[b * 104 + e];
    float w = wlist[b * 104 + e];
    if (s == 0) {
      r += w * A0[(size_t)i * NN + j];
    } else {
      int t = s - 1;
      float pmi = pm[(size_t)(t * BB + b) * NN + i];
      float pmj = pm[(size_t)(t * BB + b) * NN + j];
      r += w * fast_sigmoid(__fmul_rn(pmi, pmj));
    }
  }
  out[((size_t)b * NN + i) * NN + j] = r * 0.01f;
}

extern "C" void kernel_launch(void* const* d_in, const int* in_sizes, int n_in,
                              void* d_out, int out_size, void* d_ws, size_t ws_size,
                              hipStream_t stream) {
  const float* mu  = (const float*)d_in[0];
  const float* sig = (const float*)d_in[1];
  const float* pi  = (const float*)d_in[2];
  const float* A0  = (const float*)d_in[3];

  char* ws = (char*)d_ws;
  size_t off = 0;
  auto alloc = [&](size_t bytes) -> char* {
    char* p = ws + off;
    off += (bytes + 255) & ~(size_t)255;
    return p;
  };
  float* llt   = (float*)alloc((size_t)T_STEPS * BB * NN * 4); // 819,200
  float* tsum  = (float*)alloc((size_t)T_STEPS * NN * 4);      // 204,800
  float* ll0   = (float*)alloc(BB * NN * 4);                   // 8,192
  float* pm    = (float*)alloc((size_t)T_STEPS * BB * NN * 4); // 819,200
  float* Lf    = (float*)alloc(BB * NN * 4);
  float* uacc  = (float*)alloc(T_STEPS * 4 * 4);
  int*   slist = (int*)alloc(BB * 104 * 4);
  float* wlist = (float*)alloc(BB * 104 * 4);
  int*   Mv    = (int*)alloc(4 * 4);
  float* outp  = (float*)d_out;

  rng_kernel<<<(T_STEPS * BB * NN + 255) / 256, 256, 0, stream>>>(mu, sig, pi,
                                                                  pm, uacc, Lf);
  ll_kernel<<<416, 512, 0, stream>>>(pm, Lf, A0, llt, ll0, tsum);
  chain_kernel<<<1, 64, 0, stream>>>(llt, tsum, ll0, uacc, slist, wlist, Mv);
  out_kernel<<<BB * NN, 512, 0, stream>>>(pm, A0, slist, wlist, Mv, outp);
}